// Round 14
// baseline (53.991 us; speedup 1.0000x reference)
//
#include <hip/hip_runtime.h>
#include <hip/hip_bf16.h>

#define NUM_OPS 8
#define D 1024
#define B_ROWS 8192

typedef unsigned short ushort_t;
typedef __attribute__((ext_vector_type(8))) short bf16x8;
typedef __attribute__((ext_vector_type(4))) float f32x4;
typedef __attribute__((ext_vector_type(4))) float float4v;
typedef __attribute__((ext_vector_type(8))) unsigned short ushort8;

__device__ __forceinline__ unsigned short f2bf(float f) {
    union { float f; unsigned int u; } v; v.f = f;
    unsigned int u = v.u;
    unsigned int lsb = (u >> 16) & 1u;
    u += 0x7fffu + lsb;   // round-to-nearest-even
    return (unsigned short)(u >> 16);
}

__device__ __forceinline__ void load_lds16(const void* g, void* l) {
    __builtin_amdgcn_global_load_lds(
        (const __attribute__((address_space(1))) void*)g,
        (__attribute__((address_space(3))) void*)l,
        16, 0, 0);
}

// deterministic top-2 (matches jax top_k tie-breaking: earliest index wins)
__device__ __forceinline__ void top2(const float* __restrict__ logits, int& i0, int& i1) {
    float best = -__builtin_inff(); i0 = 0;
    for (int i = 0; i < NUM_OPS; ++i) { float v = logits[i]; if (v > best) { best = v; i0 = i; } }
    float best2 = -__builtin_inff(); i1 = 0;
    for (int i = 0; i < NUM_OPS; ++i) {
        if (i == i0) continue;
        float v = logits[i]; if (v > best2) { best2 = v; i1 = i; }
    }
}

// ---------------- x : f32 -> bf16 (linear row-major) ----------------
__global__ void convert_x(const float* __restrict__ x, ushort_t* __restrict__ xb) {
    int i = (blockIdx.x * 256 + threadIdx.x) * 8;
    float4v v0 = *(const float4v*)(x + i);
    float4v v1 = *(const float4v*)(x + i + 4);
    ushort8 o;
    o[0] = f2bf(v0[0]); o[1] = f2bf(v0[1]); o[2] = f2bf(v0[2]); o[3] = f2bf(v0[3]);
    o[4] = f2bf(v1[0]); o[5] = f2bf(v1[1]); o[6] = f2bf(v1[2]); o[7] = f2bf(v1[3]);
    *(ushort8*)(xb + i) = o;
}

// ------- gather selected experts' W, transpose to [n][k], cast bf16 -------
__global__ void gather_transpose_W(const float* __restrict__ Ws,
                                   const float* __restrict__ logits,
                                   ushort_t* __restrict__ Wt) {
    __shared__ float t[32][33];
    int i0, i1; top2(logits, i0, i1);
    int e    = blockIdx.x >> 10;
    int tile = blockIdx.x & 1023;
    int td = (tile >> 5) << 5;
    int te = (tile & 31) << 5;
    int tx = threadIdx.x & 31, ty = threadIdx.x >> 5;
    const float* W = Ws + (size_t)(e ? i1 : i0) * D * D;
    for (int r = 0; r < 4; ++r)
        t[ty + 8 * r][tx] = W[(size_t)(td + ty + 8 * r) * D + te + tx];
    __syncthreads();
    ushort_t* o = Wt + (size_t)e * D * D;
    for (int r = 0; r < 4; ++r)
        o[(size_t)(te + ty + 8 * r) * D + td + tx] = f2bf(t[tx][ty + 8 * r]);
}

// -------- staging: linear LDS dest, inverse-XOR-swizzled global source -----
// (verbatim r9, verified) LDS row = 128B; byte (r*128+c') holds global
// col-byte (c' ^ ((r&7)<<4)).
__device__ __forceinline__ void stageA(const ushort_t* __restrict__ xbf, int brow,
                                       int u, ushort_t* dst, int tid) {
    #pragma unroll
    for (int q = 0; q < 4; ++q) {                       // 256 rows x 128B = 32KB
        const int c   = q * 512 + tid;
        const int rr  = c >> 3;
        const int gcb = ((c & 7) * 16) ^ ((rr & 7) << 4);
        load_lds16(xbf + (size_t)(brow + rr) * D + u * 64 + (gcb >> 1), dst + c * 8);
    }
}
__device__ __forceinline__ void stageB(const ushort_t* __restrict__ Wt, int bcol,
                                       int u, ushort_t* dst, int tid) {
    #pragma unroll
    for (int q = 0; q < 2; ++q) {                       // 2e x 64 rows x 128B = 16KB
        const int c   = q * 512 + tid;
        const int e   = c >> 9, cc = c & 511;
        const int n   = cc >> 3;
        const int gcb = ((cc & 7) * 16) ^ ((n & 7) << 4);
        load_lds16(Wt + (size_t)e * D * D + (size_t)(bcol + n) * D + u * 64 + (gcb >> 1),
                   dst + c * 8);
    }
}

#define SB()    __builtin_amdgcn_sched_barrier(0)
#define PRIO1() __builtin_amdgcn_s_setprio(1)
#define PRIO0() __builtin_amdgcn_s_setprio(0)
#define VM0()   do { asm volatile("s_waitcnt vmcnt(0)" ::: "memory"); } while (0)

// read one fragment set (8 A + 8 B b128, swizzled) from slot (CA, CB)
#define READF(AF, BF, CA, CB)                                                      \
    do {                                                                           \
        _Pragma("unroll") for (int kk = 0; kk < 2; ++kk)                           \
        _Pragma("unroll") for (int m = 0; m < 4; ++m)                              \
            AF[kk][m] = *(const bf16x8*)((const char*)(CA) +                       \
                (size_t)((rgrp * 64 + m * 16 + l15) * 128) + (kk ? x1 : x0));      \
        _Pragma("unroll") for (int e = 0; e < 2; ++e)                              \
        _Pragma("unroll") for (int kk = 0; kk < 2; ++kk)                           \
        _Pragma("unroll") for (int n16 = 0; n16 < 2; ++n16)                        \
            BF[e][kk][n16] = *(const bf16x8*)((const char*)(CB) + e * 8192 +       \
                (size_t)((cgrp * 32 + n16 * 16 + l15) * 128) + (kk ? x1 : x0));    \
    } while (0)

// 32 MFMA on a named set (compiler inserts counted lgkm for these regs)
#define MM32(AF, BF)                                                               \
    do {                                                                           \
        PRIO1();                                                                   \
        _Pragma("unroll") for (int kk = 0; kk < 2; ++kk)                           \
        _Pragma("unroll") for (int e = 0; e < 2; ++e)                              \
        _Pragma("unroll") for (int m = 0; m < 4; ++m)                              \
        _Pragma("unroll") for (int n16 = 0; n16 < 2; ++n16)                        \
            acc[e][m][n16] = __builtin_amdgcn_mfma_f32_16x16x32_bf16(              \
                AF[kk][m], BF[e][kk][n16], acc[e][m][n16], 0, 0, 0);               \
        PRIO0();                                                                   \
    } while (0)

// one K-tile u:
//   vmcnt(0)   -- drains stage(u+1) (issued a full tile ago -> ~free)
//   barrier    -- slot (u+1)%3 now valid for all waves; all reads of slot
//                 (u+2)%3 completed (forced before MFMA(u-1))
//   ds_read F(u+1)  -- 16 b128, NOT waited: they fly under MFMA(u)
//   stage(u+2)      -- 6 global_load_lds into slot (u+2)%3 (safe, see above)
//   sched_barrier; MFMA(F(u)) -- compiler emits lgkmcnt(16): waits only F(u)
#define TILE(FR_A, FR_B, SLOT_RA, SLOT_RB, FC_A, FC_B, SU, DA, DB, DORD, DOSTG)    \
    do {                                                                           \
        VM0();                                                                     \
        __builtin_amdgcn_s_barrier();                                              \
        if (DORD) READF(FR_A, FR_B, SLOT_RA, SLOT_RB);                             \
        if (DOSTG) { stageA(xbf, brow, (SU), DA, tid);                             \
                     stageB(Wt,  bcol, (SU), DB, tid); }                           \
        SB();                                                                      \
        MM32(FC_A, FC_B);                                                          \
    } while (0)

// -------- fused dual-expert GEMM: reg-dbuf fragments, ring-3 LDS ------------
// Block: 256 rows x 64 cols x 2 experts, 8 waves (4r x 2c), BK=64 (r9 base).
// KEY CHANGE vs r9: tile u+1's LDS->reg fragment reads are issued BEFORE
// MFMA(u) and only waited (counted lgkm) at tile u+1 -> LDS-read throughput
// (~1500 cyc/tile/CU) overlaps the MFMA window (~1240 cyc) instead of adding.
__global__ __launch_bounds__(512, 2)
void gemm_dual(const ushort_t* __restrict__ xbf, const ushort_t* __restrict__ Wt,
               const float* __restrict__ bs, const float* __restrict__ logits,
               float* __restrict__ out) {
    __shared__ __align__(16) ushort_t As0[256 * 64], As1[256 * 64], As2[256 * 64];
    __shared__ __align__(16) ushort_t Bs0[2 * 64 * 64], Bs1[2 * 64 * 64], Bs2[2 * 64 * 64];

    const int tid  = threadIdx.x;
    const int wv   = tid >> 6;
    const int lane = tid & 63;
    const int rgrp = wv >> 1, cgrp = wv & 1;
    const int l15  = lane & 15, lq = lane >> 4;
    const int swz  = (l15 & 7) << 4;
    const int x0   = (lq * 16) ^ swz;
    const int x1   = (64 + lq * 16) ^ swz;

    const int bid  = blockIdx.x;
    const int brow = (bid & 31) * 256;
    const int bcol = (bid >> 5) * 64;

    f32x4 acc[2][4][2] = {};
    bf16x8 a0[2][4], b0[2][2][2];   // fragment set 0
    bf16x8 a1[2][4], b1[2][2][2];   // fragment set 1

    // prologue: stage tiles 0,1; verify tile 0 (vmcnt(6) keeps stage(1) in
    // flight); read F0
    stageA(xbf, brow, 0, As0, tid); stageB(Wt, bcol, 0, Bs0, tid);
    stageA(xbf, brow, 1, As1, tid); stageB(Wt, bcol, 1, Bs1, tid);
    SB();
    asm volatile("s_waitcnt vmcnt(6)" ::: "memory");
    __builtin_amdgcn_s_barrier();
    READF(a0, b0, As0, Bs0);
    SB();

    //    FR     slot-read   FC      stage-u  dst      read? stage?
    TILE(a1, b1, As1, Bs1, a0, b0,  2, As2, Bs2, true,  true);   // u=0
    TILE(a0, b0, As2, Bs2, a1, b1,  3, As0, Bs0, true,  true);   // u=1
    TILE(a1, b1, As0, Bs0, a0, b0,  4, As1, Bs1, true,  true);   // u=2
    TILE(a0, b0, As1, Bs1, a1, b1,  5, As2, Bs2, true,  true);   // u=3
    TILE(a1, b1, As2, Bs2, a0, b0,  6, As0, Bs0, true,  true);   // u=4
    TILE(a0, b0, As0, Bs0, a1, b1,  7, As1, Bs1, true,  true);   // u=5
    TILE(a1, b1, As1, Bs1, a0, b0,  8, As2, Bs2, true,  true);   // u=6
    TILE(a0, b0, As2, Bs2, a1, b1,  9, As0, Bs0, true,  true);   // u=7
    TILE(a1, b1, As0, Bs0, a0, b0, 10, As1, Bs1, true,  true);   // u=8
    TILE(a0, b0, As1, Bs1, a1, b1, 11, As2, Bs2, true,  true);   // u=9
    TILE(a1, b1, As2, Bs2, a0, b0, 12, As0, Bs0, true,  true);   // u=10
    TILE(a0, b0, As0, Bs0, a1, b1, 13, As1, Bs1, true,  true);   // u=11
    TILE(a1, b1, As1, Bs1, a0, b0, 14, As2, Bs2, true,  true);   // u=12
    TILE(a0, b0, As2, Bs2, a1, b1, 15, As0, Bs0, true,  true);   // u=13
    TILE(a1, b1, As0, Bs0, a0, b0,  0, As0, Bs0, true,  false);  // u=14 (read F(15))
    TILE(a0, b0, As0, Bs0, a1, b1,  0, As0, Bs0, false, false);  // u=15

    // ---- epilogue: per-expert bias + relu, sum, store f32 (r9-verified)
    int i0, i1; top2(logits, i0, i1);
    #pragma unroll
    for (int n16 = 0; n16 < 2; ++n16) {
        const int col = bcol + cgrp * 32 + n16 * 16 + l15;
        const float bb0 = bs[i0 * D + col];
        const float bb1 = bs[i1 * D + col];
        #pragma unroll
        for (int m = 0; m < 4; ++m) {
            const int rbase = brow + rgrp * 64 + m * 16 + lq * 4;
            #pragma unroll
            for (int i = 0; i < 4; ++i) {
                float v0 = acc[0][m][n16][i] + bb0; v0 = v0 > 0.f ? v0 : 0.f;
                float v1 = acc[1][m][n16][i] + bb1; v1 = v1 > 0.f ? v1 : 0.f;
                out[(size_t)(rbase + i) * D + col] = v0 + v1;
            }
        }
    }
}

extern "C" void kernel_launch(void* const* d_in, const int* in_sizes, int n_in,
                              void* d_out, int out_size, void* d_ws, size_t ws_size,
                              hipStream_t stream) {
    const float* x      = (const float*)d_in[0];
    const float* logits = (const float*)d_in[1];
    const float* Ws     = (const float*)d_in[2];
    const float* bs     = (const float*)d_in[3];
    float* out = (float*)d_out;

    char* ws = (char*)d_ws;
    ushort_t* xbf = (ushort_t*)ws;                                   // 16 MB
    ushort_t* Wt  = (ushort_t*)(ws + (size_t)B_ROWS * D * 2);        //  4 MB

    convert_x<<<(B_ROWS * D) / (256 * 8), 256, 0, stream>>>(x, xbf);
    gather_transpose_W<<<2 * (D / 32) * (D / 32), 256, 0, stream>>>(Ws, logits, Wt);

    gemm_dual<<<512, 512, 0, stream>>>(xbf, Wt, bs, logits, out);
}